// Round 7
// baseline (194.163 us; speedup 1.0000x reference)
//
#include <hip/hip_runtime.h>
#include <math.h>

typedef __bf16 bf16;
typedef __bf16 bf16x4 __attribute__((ext_vector_type(4)));
typedef __bf16 bf16x8 __attribute__((ext_vector_type(8)));
typedef float f32x4 __attribute__((ext_vector_type(4)));

#define MFMA(a, b, c) __builtin_amdgcn_mfma_f32_16x16x32_bf16(a, b, c, 0, 0, 0)
#define LOG2E 1.44269504088896340736f

// XOR-swizzled 64x64 bf16 tile (8 KB): elem (row, chunk8) at row*64 + ((ch^(row&7))*8).
// Coalesced staging writes, ~conflict-free b128 fragment reads (2-way max, free per m136).
__device__ __forceinline__ void stage_tile256(bf16* __restrict__ T, const bf16* __restrict__ src,
                                              int rs, int t) {
#pragma unroll
    for (int it = 0; it < 2; ++it) {
        int u = it * 256 + t;
        int row = u >> 3, ch = u & 7;
        bf16x8 v = *(const bf16x8*)&src[(size_t)row * rs + ch * 8];
        *(bf16x8*)&T[row * 64 + ((ch ^ (row & 7)) << 3)] = v;
    }
}
__device__ __forceinline__ void stage_tile512(bf16* __restrict__ T, const bf16* __restrict__ src,
                                              int rs, int t) {
    int row = t >> 3, ch = t & 7;
    bf16x8 v = *(const bf16x8*)&src[(size_t)row * rs + ch * 8];
    *(bf16x8*)&T[row * 64 + ((ch ^ (row & 7)) << 3)] = v;
}
__device__ __forceinline__ bf16x8 frag(const bf16* __restrict__ T, int row, int ch) {
    return *(const bf16x8*)&T[row * 64 + ((ch ^ (row & 7)) << 3)];
}

// ---------------- fused preprocessing ----------------
// [0,2048): ballot mask pack; [2048,3072): x->bf16; [3072,3584): weights; [3584,4104): zero Osum/Lsum.
__global__ __launch_bounds__(256) void prep(
    const int* __restrict__ seqm, const int* __restrict__ spm,
    const float* __restrict__ x,
    const float* __restrict__ Wq, const float* __restrict__ Wk,
    const float* __restrict__ Wv, const float* __restrict__ Wo,
    unsigned* __restrict__ pseq, unsigned* __restrict__ psp,
    bf16* __restrict__ xb, bf16* __restrict__ Wb,
    bf16* __restrict__ Woh, bf16* __restrict__ Wol,
    float* __restrict__ Osum)   // Osum followed by Lsum (zeroed together)
{
    int bid = blockIdx.x, t = threadIdx.x;
    if (bid < 2048) {
        int wave = t >> 6, lane = t & 63;
        int row = bid * 4 + wave;
        const int* src = (row < 4096) ? (seqm + (size_t)row * 2048)
                                      : (spm + (size_t)(row - 4096) * 2048);
        unsigned* dst = (row < 4096) ? (pseq + (size_t)row * 64)
                                     : (psp + (size_t)(row - 4096) * 64);
        unsigned myw = 0;
#pragma unroll
        for (int u = 0; u < 32; ++u) {
            int v = src[u * 64 + lane];
            unsigned long long bal = __ballot(v != 0);
            if ((lane >> 1) == u)
                myw = (lane & 1) ? (unsigned)(bal >> 32) : (unsigned)bal;
        }
        dst[lane] = myw;
    } else if (bid < 3072) {
        int i = ((bid - 2048) * 256 + t) * 8;
        float4 a = *(const float4*)&x[i];
        float4 c = *(const float4*)&x[i + 4];
        float v[8] = {a.x, a.y, a.z, a.w, c.x, c.y, c.z, c.w};
        bf16x8 o;
#pragma unroll
        for (int u = 0; u < 8; ++u) o[u] = (bf16)v[u];
        *(bf16x8*)&xb[i] = o;
    } else if (bid < 3584) {
        int zb = bid - 3072;
        int z = zb >> 7;
        int i = ((zb & 127) * 256 + t) * 8;
        const float* src = (z == 0) ? Wq : (z == 1) ? Wk : (z == 2) ? Wv : Wo;
        float4 a = *(const float4*)&src[i];
        float4 c = *(const float4*)&src[i + 4];
        float v[8] = {a.x, a.y, a.z, a.w, c.x, c.y, c.z, c.w};
        if (z < 3) {
            bf16x8 o;
#pragma unroll
            for (int u = 0; u < 8; ++u) o[u] = (bf16)v[u];
            *(bf16x8*)&Wb[(size_t)z * 262144 + i] = o;
        } else {
            bf16x8 oh, ol;
#pragma unroll
            for (int u = 0; u < 8; ++u) {
                bf16 hi = (bf16)v[u];
                oh[u] = hi;
                ol[u] = (bf16)(v[u] - (float)hi);
            }
            *(bf16x8*)&Woh[i] = oh;
            *(bf16x8*)&Wol[i] = ol;
        }
    } else {
        // zero Osum (2,097,152 f32) + Lsum (32,768 f32): 520 blocks x 4096 floats
        size_t off = (size_t)(bid - 3584) * 4096 + t * 16;
        float4 z4 = make_float4(0.f, 0.f, 0.f, 0.f);
#pragma unroll
        for (int u = 0; u < 4; ++u) *(float4*)&Osum[off + u * 4] = z4;
    }
}

// ---------------- fused QKV projection (Q pre-scaled by 0.125*log2e) ----------------
__global__ __launch_bounds__(256) void gemm_qkv(
    const bf16* __restrict__ A, const bf16* __restrict__ Wb,
    bf16* __restrict__ Qg, bf16* __restrict__ Kg, bf16* __restrict__ Vt)
{
    __shared__ bf16 AT[4096], WT[4096];
    __shared__ bf16 Lt[64 * 72];
    int bid = blockIdx.x;
    int m0b = bid & 63;
    int rest = bid >> 6;
    int n0 = rest & 7, z = rest >> 3;
    const bf16* W = Wb + (size_t)z * 262144;
    float scale = (z == 0) ? (0.125f * LOG2E) : 1.0f;

    int t = threadIdx.x, wave = t >> 6, lane = t & 63, l = lane & 15, quad = lane >> 4;
    int m0 = m0b * 64 + wave * 16;
    int nb = n0 * 64;
    f32x4 acc[4] = {};
    for (int k0 = 0; k0 < 512; k0 += 64) {
        __syncthreads();
        stage_tile256(AT, A + (size_t)m0b * 64 * 512 + k0, 512, t);
        stage_tile256(WT, W + (size_t)nb * 512 + k0, 512, t);
        __syncthreads();
        bf16x8 a0 = frag(AT, wave * 16 + l, quad);
        bf16x8 a1 = frag(AT, wave * 16 + l, 4 + quad);
#pragma unroll
        for (int nc = 0; nc < 4; ++nc) {
            bf16x8 b0 = frag(WT, nc * 16 + l, quad);
            bf16x8 b1 = frag(WT, nc * 16 + l, 4 + quad);
            acc[nc] = MFMA(a0, b0, acc[nc]);
            acc[nc] = MFMA(a1, b1, acc[nc]);
        }
    }
    if (z < 2) {
        bf16* out = (z == 0) ? Qg : Kg;
#pragma unroll
        for (int nc = 0; nc < 4; ++nc) {
#pragma unroll
            for (int r = 0; r < 4; ++r) {
                int m = m0 + quad * 4 + r;
                int feat = nb + nc * 16 + l;
                int b = m >> 11, tok = m & 2047, h = feat >> 6, d = feat & 63;
                out[(((size_t)(b * 8 + h)) * 2048 + tok) * 64 + d] = (bf16)(acc[nc][r] * scale);
            }
        }
    } else {
        __syncthreads();
#pragma unroll
        for (int nc = 0; nc < 4; ++nc)
#pragma unroll
            for (int r = 0; r < 4; ++r)
                Lt[(nc * 16 + l) * 72 + wave * 16 + quad * 4 + r] = (bf16)acc[nc][r];
        __syncthreads();
        int d = t >> 2, seg = t & 3;
        int tok0 = m0b * 64;
        int b = tok0 >> 11, h = n0;
        bf16x8 o0, o1;
#pragma unroll
        for (int i = 0; i < 8; ++i) { o0[i] = Lt[d * 72 + seg * 16 + i]; o1[i] = Lt[d * 72 + seg * 16 + 8 + i]; }
        size_t base = ((size_t)(b * 8 + h) * 64 + d) * 2048 + (tok0 & 2047) + seg * 16;
        *(bf16x8*)&Vt[base] = o0;
        *(bf16x8*)&Vt[base + 8] = o1;
    }
}

// ---------------- flash attention: 128 q-rows/block, j-split x4, atomic fp32 accumulate ----------------
// grid 1024 = jc(2b) | it(4b) | bh(4b); 512 thr = 8 waves (16 rows each).
// LDS 34 KB -> 4 blocks/CU = 32 waves/CU. p = bit ? exp2(s) : 0 (Q pre-scaled by log2e).
__global__ __launch_bounds__(512) void attn_kernel(
    const bf16* __restrict__ Qg, const bf16* __restrict__ Kg, const bf16* __restrict__ Vt,
    const unsigned* __restrict__ pseq, const unsigned* __restrict__ psp,
    float* __restrict__ Osum, float* __restrict__ Lsum)
{
    __shared__ bf16 KT[4096], VT[4096];
    __shared__ bf16 P[8 * 16 * 72];
    int bid = blockIdx.x;
    int bh = bid & 15;                       // XCD = bid%8 -> K/V L2-resident
    int it = (bid >> 4) & 15;
    int jc = bid >> 8;
    int i0 = it * 128;
    int b = bh >> 3, par = bh & 1;
    int t = threadIdx.x, rg = t >> 6, lane = t & 63, l = lane & 15, quad = lane >> 4;

    const bf16* Qp = Qg + ((size_t)bh * 2048 + i0 + rg * 16 + l) * 64;
    bf16x8 qf0 = *(const bf16x8*)&Qp[quad * 8];
    bf16x8 qf1 = *(const bf16x8*)&Qp[32 + quad * 8];

    bf16x8 ones;
#pragma unroll
    for (int i = 0; i < 8; ++i) ones[i] = (bf16)1.0f;

    f32x4 o_acc[4] = {}, l_acc = {};

    int qrow = i0 + rg * 16 + l;
    const unsigned* seqp = pseq + (size_t)b * 131072 + (size_t)qrow * 64;
    const unsigned* sppp = psp + (size_t)par * 131072 + (size_t)qrow * 64;
    const bf16* Kbase = Kg + (size_t)bh * 2048 * 64;
    const bf16* Vbase = Vt + (size_t)bh * 64 * 2048;
    bf16* Pw = P + rg * 1152 + l * 72;
    const bf16* Pr = P + rg * 1152;

    int jlo = jc * 512, jhi = jlo + 512;
    for (int j0 = jlo; j0 < jhi; j0 += 64) {
        uint2 mseq = *(const uint2*)&seqp[j0 >> 5];
        uint2 msp = *(const uint2*)&sppp[j0 >> 5];
        unsigned w0 = mseq.x & msp.x, w1 = mseq.y & msp.y;

        __syncthreads();
        stage_tile512(KT, Kbase + (size_t)j0 * 64, 64, t);
        stage_tile512(VT, Vbase + j0, 2048, t);
        __syncthreads();

        // S^T = K·Q^T (col = query lane)
        f32x4 s[4] = {};
#pragma unroll
        for (int nc = 0; nc < 4; ++nc) {
            bf16x8 k0f = frag(KT, nc * 16 + l, quad);
            bf16x8 k1f = frag(KT, nc * 16 + l, 4 + quad);
            s[nc] = MFMA(k0f, qf0, s[nc]);
            s[nc] = MFMA(k1f, qf1, s[nc]);
        }

        // fixed-max softmax: p = bit ? exp2(s) : 0
#pragma unroll
        for (int nc = 0; nc < 4; ++nc) {
            unsigned w = (nc < 2) ? w0 : w1;
            int bbase = (nc & 1) * 16 + quad * 4;
            bf16x4 pv;
#pragma unroll
            for (int r = 0; r < 4; ++r) {
                float e = exp2f(s[nc][r]);
                pv[r] = (bf16)(((w >> (bbase + r)) & 1u) ? e : 0.f);
            }
            *(bf16x4*)&Pw[nc * 16 + quad * 4] = pv;
        }

        bf16x8 pa0 = *(const bf16x8*)&Pr[l * 72 + quad * 8];
        bf16x8 pa1 = *(const bf16x8*)&Pr[l * 72 + 32 + quad * 8];
        l_acc = MFMA(pa0, ones, l_acc);
        l_acc = MFMA(pa1, ones, l_acc);
#pragma unroll
        for (int dc = 0; dc < 4; ++dc) {
            bf16x8 vb0 = frag(VT, dc * 16 + l, quad);
            bf16x8 vb1 = frag(VT, dc * 16 + l, 4 + quad);
            o_acc[dc] = MFMA(pa0, vb0, o_acc[dc]);
            o_acc[dc] = MFMA(pa1, vb1, o_acc[dc]);
        }
    }

    // atomic fp32 accumulate into Osum[bh][it32][row][d], Lsum[bh][it32][row]
    int it32 = it * 2 + (rg >> 2);
    int rowin = (rg & 3) * 16;
    float* Ob = Osum + ((size_t)(bh * 32 + it32)) * 4096;
#pragma unroll
    for (int r = 0; r < 4; ++r) {
        int row = rowin + quad * 4 + r;
#pragma unroll
        for (int dc = 0; dc < 4; ++dc)
            atomicAdd(&Ob[(size_t)row * 64 + dc * 16 + l], o_acc[dc][r]);
        if (l == 0)
            atomicAdd(&Lsum[(bh * 32 + it32) * 64 + row], l_acc[r]);
    }
}

// ---------------- output projection with fused normalize + hi/lo split ----------------
// A[m][k] = Osum[b, h(k), tok, d] / Lsum; C = A@Wo^T in split-bf16 (3 MFMA terms).
__global__ __launch_bounds__(256) void gemm_out(
    const float* __restrict__ Osum, const float* __restrict__ Lsum,
    const bf16* __restrict__ Wh, const bf16* __restrict__ Wl,
    float* __restrict__ C)
{
    __shared__ bf16 AhT[4096], AlT[4096], WhT[4096], WlT[4096];
    __shared__ float Linv[512];
    int bid = blockIdx.x;
    int m0b = bid & 63, n0 = bid >> 6;       // same m0b -> same XCD (A-tile L2 reuse)
    int t = threadIdx.x, wave = t >> 6, lane = t & 63, l = lane & 15, quad = lane >> 4;
    int m0 = m0b * 64 + wave * 16;
    int nb = n0 * 64;
    int b = m0b >> 5, itA = m0b & 31;

    // per-block inverse-l table: [h][row]
    {
        int h = t >> 6, row = t & 63;
        Linv[t] = 1.0f / Lsum[((b * 8 + h) * 32 + itA) * 64 + row];
        Linv[256 + t] = 1.0f / Lsum[((b * 8 + 4 + h) * 32 + itA) * 64 + row];
    }

    f32x4 acc[4] = {};
    for (int k0 = 0; k0 < 512; k0 += 64) {
        int h = k0 >> 6;
        const float* Ab = Osum + ((size_t)((b * 8 + h) * 32 + itA)) * 4096;
        __syncthreads();
        // stage normalized hi/lo A tile + W tiles
#pragma unroll
        for (int itr = 0; itr < 2; ++itr) {
            int u = itr * 256 + t;
            int row = u >> 3, ch = u & 7;
            float4 v0 = *(const float4*)&Ab[(size_t)row * 64 + ch * 8];
            float4 v1 = *(const float4*)&Ab[(size_t)row * 64 + ch * 8 + 4];
            float inv = Linv[h * 64 + row];
            float vv[8] = {v0.x, v0.y, v0.z, v0.w, v1.x, v1.y, v1.z, v1.w};
            bf16x8 hi, lo;
#pragma unroll
            for (int i = 0; i < 8; ++i) {
                float o = vv[i] * inv;
                bf16 hb = (bf16)o;
                hi[i] = hb;
                lo[i] = (bf16)(o - (float)hb);
            }
            int dst = row * 64 + ((ch ^ (row & 7)) << 3);
            *(bf16x8*)&AhT[dst] = hi;
            *(bf16x8*)&AlT[dst] = lo;
        }
        stage_tile256(WhT, Wh + (size_t)nb * 512 + k0, 512, t);
        stage_tile256(WlT, Wl + (size_t)nb * 512 + k0, 512, t);
        __syncthreads();
        bf16x8 ah0 = frag(AhT, wave * 16 + l, quad);
        bf16x8 ah1 = frag(AhT, wave * 16 + l, 4 + quad);
        bf16x8 al0 = frag(AlT, wave * 16 + l, quad);
        bf16x8 al1 = frag(AlT, wave * 16 + l, 4 + quad);
#pragma unroll
        for (int nc = 0; nc < 4; ++nc) {
            bf16x8 bh0 = frag(WhT, nc * 16 + l, quad);
            bf16x8 bh1 = frag(WhT, nc * 16 + l, 4 + quad);
            bf16x8 bl0 = frag(WlT, nc * 16 + l, quad);
            bf16x8 bl1 = frag(WlT, nc * 16 + l, 4 + quad);
            acc[nc] = MFMA(ah0, bh0, acc[nc]);
            acc[nc] = MFMA(ah1, bh1, acc[nc]);
            acc[nc] = MFMA(ah0, bl0, acc[nc]);
            acc[nc] = MFMA(ah1, bl1, acc[nc]);
            acc[nc] = MFMA(al0, bh0, acc[nc]);
            acc[nc] = MFMA(al1, bh1, acc[nc]);
        }
    }
#pragma unroll
    for (int nc = 0; nc < 4; ++nc)
#pragma unroll
        for (int r = 0; r < 4; ++r)
            C[(size_t)(m0 + quad * 4 + r) * 512 + nb + nc * 16 + l] = acc[nc][r];
}

extern "C" void kernel_launch(void* const* d_in, const int* in_sizes, int n_in,
                              void* d_out, int out_size, void* d_ws, size_t ws_size,
                              hipStream_t stream) {
    const float* x = (const float*)d_in[0];
    const float* Wq = (const float*)d_in[1];
    const float* Wk = (const float*)d_in[2];
    const float* Wv = (const float*)d_in[3];
    const float* Wo = (const float*)d_in[4];
    const int* seqm = (const int*)d_in[5];
    const int* spm = (const int*)d_in[6];
    float* out = (float*)d_out;

    const size_t E = 2097152;            // 2*2048*512
    bf16* xb = (bf16*)d_ws;
    bf16* Wb = xb + E;
    bf16* Woh = Wb + 786432;
    bf16* Wol = Woh + 262144;
    bf16* Qg = Wol + 262144;
    bf16* Kg = Qg + E;
    bf16* Vtg = Kg + E;                  // [bh][64][2048]
    unsigned* pseq = (unsigned*)(Vtg + E);
    unsigned* psp = pseq + 262144;
    float* Osum = (float*)(psp + 262144);        // [16][32][64][64] fp32 = 8 MB
    float* Lsum = Osum + (size_t)16 * 32 * 4096; // [16][32][64] fp32 = 128 KB

    hipLaunchKernelGGL(prep, dim3(4104), dim3(256), 0, stream,
                       seqm, spm, x, Wq, Wk, Wv, Wo, pseq, psp, xb, Wb, Woh, Wol, Osum);
    hipLaunchKernelGGL(gemm_qkv, dim3(1536), dim3(256), 0, stream, xb, Wb, Qg, Kg, Vtg);
    hipLaunchKernelGGL(attn_kernel, dim3(1024), dim3(512), 0, stream,
                       Qg, Kg, Vtg, pseq, psp, Osum, Lsum);
    hipLaunchKernelGGL(gemm_out, dim3(512), dim3(256), 0, stream, Osum, Lsum, Woh, Wol, out);
}

// Round 8
// 176.543 us; speedup vs baseline: 1.0998x; 1.0998x over previous
//
#include <hip/hip_runtime.h>
#include <math.h>

typedef __bf16 bf16;
typedef __bf16 bf16x4 __attribute__((ext_vector_type(4)));
typedef __bf16 bf16x8 __attribute__((ext_vector_type(8)));
typedef float f32x4 __attribute__((ext_vector_type(4)));

#define MFMA(a, b, c) __builtin_amdgcn_mfma_f32_16x16x32_bf16(a, b, c, 0, 0, 0)
#define LOG2E 1.44269504088896340736f

// XOR-swizzled 64x64 bf16 tile (8 KB): elem (row, chunk8) at row*64 + ((ch^(row&7))*8).
// Coalesced staging writes, ~conflict-free b128 fragment reads (2-way max, free per m136).
__device__ __forceinline__ void stage_tile256(bf16* __restrict__ T, const bf16* __restrict__ src,
                                              int rs, int t) {
#pragma unroll
    for (int it = 0; it < 2; ++it) {
        int u = it * 256 + t;
        int row = u >> 3, ch = u & 7;
        bf16x8 v = *(const bf16x8*)&src[(size_t)row * rs + ch * 8];
        *(bf16x8*)&T[row * 64 + ((ch ^ (row & 7)) << 3)] = v;
    }
}
__device__ __forceinline__ bf16x8 frag(const bf16* __restrict__ T, int row, int ch) {
    return *(const bf16x8*)&T[row * 64 + ((ch ^ (row & 7)) << 3)];
}

// ---------------- fused preprocessing (R6) ----------------
__global__ __launch_bounds__(256) void prep(
    const int* __restrict__ seqm, const int* __restrict__ spm,
    const float* __restrict__ x,
    const float* __restrict__ Wq, const float* __restrict__ Wk,
    const float* __restrict__ Wv, const float* __restrict__ Wo,
    unsigned* __restrict__ pseq, unsigned* __restrict__ psp,
    bf16* __restrict__ xb, bf16* __restrict__ Wb,
    bf16* __restrict__ Woh, bf16* __restrict__ Wol)
{
    int bid = blockIdx.x, t = threadIdx.x;
    if (bid < 2048) {
        int wave = t >> 6, lane = t & 63;
        int row = bid * 4 + wave;
        const int* src = (row < 4096) ? (seqm + (size_t)row * 2048)
                                      : (spm + (size_t)(row - 4096) * 2048);
        unsigned* dst = (row < 4096) ? (pseq + (size_t)row * 64)
                                     : (psp + (size_t)(row - 4096) * 64);
        unsigned myw = 0;
#pragma unroll
        for (int u = 0; u < 32; ++u) {
            int v = src[u * 64 + lane];
            unsigned long long bal = __ballot(v != 0);
            if ((lane >> 1) == u)
                myw = (lane & 1) ? (unsigned)(bal >> 32) : (unsigned)bal;
        }
        dst[lane] = myw;
    } else if (bid < 3072) {
        int i = ((bid - 2048) * 256 + t) * 8;
        float4 a = *(const float4*)&x[i];
        float4 c = *(const float4*)&x[i + 4];
        float v[8] = {a.x, a.y, a.z, a.w, c.x, c.y, c.z, c.w};
        bf16x8 o;
#pragma unroll
        for (int u = 0; u < 8; ++u) o[u] = (bf16)v[u];
        *(bf16x8*)&xb[i] = o;
    } else {
        int zb = bid - 3072;
        int z = zb >> 7;
        int i = ((zb & 127) * 256 + t) * 8;
        const float* src = (z == 0) ? Wq : (z == 1) ? Wk : (z == 2) ? Wv : Wo;
        float4 a = *(const float4*)&src[i];
        float4 c = *(const float4*)&src[i + 4];
        float v[8] = {a.x, a.y, a.z, a.w, c.x, c.y, c.z, c.w};
        if (z < 3) {
            bf16x8 o;
#pragma unroll
            for (int u = 0; u < 8; ++u) o[u] = (bf16)v[u];
            *(bf16x8*)&Wb[(size_t)z * 262144 + i] = o;
        } else {
            bf16x8 oh, ol;
#pragma unroll
            for (int u = 0; u < 8; ++u) {
                bf16 hi = (bf16)v[u];
                oh[u] = hi;
                ol[u] = (bf16)(v[u] - (float)hi);
            }
            *(bf16x8*)&Woh[i] = oh;
            *(bf16x8*)&Wol[i] = ol;
        }
    }
}

// ---------------- fused QKV projection, 64x128 tiles ----------------
// grid 768 = m0b(64, XCD-sticky) x np(4) x z(3). 16 MFMA per 3 staged tiles.
// Q pre-scaled by 0.125*log2e (softmax uses exp2).
__global__ __launch_bounds__(256) void gemm_qkv(
    const bf16* __restrict__ A, const bf16* __restrict__ Wb,
    bf16* __restrict__ Qg, bf16* __restrict__ Kg, bf16* __restrict__ Vt)
{
    __shared__ bf16 AT[4096], WT0[4096], WT1[4096];
    __shared__ bf16 Lt[64 * 72];
    int bid = blockIdx.x;
    int m0b = bid & 63;
    int rest = bid >> 6;
    int np = rest & 3, z = rest >> 2;
    const bf16* W = Wb + (size_t)z * 262144;
    float scale = (z == 0) ? (0.125f * LOG2E) : 1.0f;

    int t = threadIdx.x, wave = t >> 6, lane = t & 63, l = lane & 15, quad = lane >> 4;
    int m0 = m0b * 64 + wave * 16;
    int nb = np * 128;
    f32x4 acc[8] = {};
    for (int k0 = 0; k0 < 512; k0 += 64) {
        __syncthreads();
        stage_tile256(AT, A + (size_t)m0b * 64 * 512 + k0, 512, t);
        stage_tile256(WT0, W + (size_t)nb * 512 + k0, 512, t);
        stage_tile256(WT1, W + (size_t)(nb + 64) * 512 + k0, 512, t);
        __syncthreads();
        bf16x8 a0 = frag(AT, wave * 16 + l, quad);
        bf16x8 a1 = frag(AT, wave * 16 + l, 4 + quad);
#pragma unroll
        for (int nc = 0; nc < 4; ++nc) {
            bf16x8 b0 = frag(WT0, nc * 16 + l, quad);
            bf16x8 b1 = frag(WT0, nc * 16 + l, 4 + quad);
            acc[nc] = MFMA(a0, b0, acc[nc]);
            acc[nc] = MFMA(a1, b1, acc[nc]);
        }
#pragma unroll
        for (int nc = 0; nc < 4; ++nc) {
            bf16x8 b0 = frag(WT1, nc * 16 + l, quad);
            bf16x8 b1 = frag(WT1, nc * 16 + l, 4 + quad);
            acc[4 + nc] = MFMA(a0, b0, acc[4 + nc]);
            acc[4 + nc] = MFMA(a1, b1, acc[4 + nc]);
        }
    }
    if (z < 2) {
        bf16* out = (z == 0) ? Qg : Kg;
#pragma unroll
        for (int nc = 0; nc < 8; ++nc) {
#pragma unroll
            for (int r = 0; r < 4; ++r) {
                int m = m0 + quad * 4 + r;
                int feat = nb + nc * 16 + l;
                int b = m >> 11, tok = m & 2047, h = feat >> 6, d = feat & 63;
                out[(((size_t)(b * 8 + h)) * 2048 + tok) * 64 + d] = (bf16)(acc[nc][r] * scale);
            }
        }
    } else {
#pragma unroll
        for (int hh = 0; hh < 2; ++hh) {
            __syncthreads();
#pragma unroll
            for (int nc = 0; nc < 4; ++nc)
#pragma unroll
                for (int r = 0; r < 4; ++r)
                    Lt[(nc * 16 + l) * 72 + wave * 16 + quad * 4 + r] = (bf16)acc[hh * 4 + nc][r];
            __syncthreads();
            int d = t >> 2, seg = t & 3;
            int tok0 = m0b * 64;
            int b = tok0 >> 11, h = np * 2 + hh;
            bf16x8 o0, o1;
#pragma unroll
            for (int i = 0; i < 8; ++i) { o0[i] = Lt[d * 72 + seg * 16 + i]; o1[i] = Lt[d * 72 + seg * 16 + 8 + i]; }
            size_t base = ((size_t)(b * 8 + h) * 64 + d) * 2048 + (tok0 & 2047) + seg * 16;
            *(bf16x8*)&Vt[base] = o0;
            *(bf16x8*)&Vt[base + 8] = o1;
        }
    }
}

// ---------------- flash attention, j-split x4, LDS-staged K/V (R6) ----------------
// grid 2048 = jc(2b) | it(5b) | bh(4b); 4 waves; LDS 25 KB -> 6 blocks/CU.
// p = bit ? exp2(s) : 0 (Q pre-scaled by log2e); score acc seeded from hoisted zero vec.
__global__ __launch_bounds__(256) void attn_kernel(
    const bf16* __restrict__ Qg, const bf16* __restrict__ Kg, const bf16* __restrict__ Vt,
    const unsigned* __restrict__ pseq, const unsigned* __restrict__ psp,
    float* __restrict__ Opart, float* __restrict__ Lpart)
{
    __shared__ bf16 KT[4096], VT[4096];
    __shared__ bf16 P[4 * 16 * 72];
    int bid = blockIdx.x;
    int bh = bid & 15;                       // XCD = bid%8 -> K/V L2-resident
    int it = (bid >> 4) & 31;
    int jc = bid >> 9;
    int i0 = it * 64;
    int b = bh >> 3, par = bh & 1;
    int t = threadIdx.x, rg = t >> 6, lane = t & 63, l = lane & 15, quad = lane >> 4;

    const bf16* Qp = Qg + ((size_t)bh * 2048 + i0 + rg * 16 + l) * 64;
    bf16x8 qf0 = *(const bf16x8*)&Qp[quad * 8];
    bf16x8 qf1 = *(const bf16x8*)&Qp[32 + quad * 8];

    bf16x8 ones;
#pragma unroll
    for (int i = 0; i < 8; ++i) ones[i] = (bf16)1.0f;
    const f32x4 fz = {0.f, 0.f, 0.f, 0.f};   // hoisted zero C operand

    f32x4 o_acc[4] = {}, l_acc = {};

    int qrow = i0 + rg * 16 + l;
    const unsigned* seqp = pseq + (size_t)b * 131072 + (size_t)qrow * 64;
    const unsigned* sppp = psp + (size_t)par * 131072 + (size_t)qrow * 64;
    const bf16* Kbase = Kg + (size_t)bh * 2048 * 64;
    const bf16* Vbase = Vt + (size_t)bh * 64 * 2048;
    bf16* Pw = P + rg * 1152 + l * 72;
    const bf16* Pr = P + rg * 1152;

    int jlo = jc * 512, jhi = jlo + 512;
    for (int j0 = jlo; j0 < jhi; j0 += 64) {
        uint2 mseq = *(const uint2*)&seqp[j0 >> 5];
        uint2 msp = *(const uint2*)&sppp[j0 >> 5];
        unsigned w0 = mseq.x & msp.x, w1 = mseq.y & msp.y;

        __syncthreads();
        stage_tile256(KT, Kbase + (size_t)j0 * 64, 64, t);
        stage_tile256(VT, Vbase + j0, 2048, t);
        __syncthreads();

        // S^T = K·Q^T (col = query lane), seeded from fz (no per-tile acc zeroing)
        f32x4 s[4];
#pragma unroll
        for (int nc = 0; nc < 4; ++nc) {
            bf16x8 k0f = frag(KT, nc * 16 + l, quad);
            bf16x8 k1f = frag(KT, nc * 16 + l, 4 + quad);
            s[nc] = MFMA(k0f, qf0, fz);
            s[nc] = MFMA(k1f, qf1, s[nc]);
        }

        // fixed-max softmax: p = bit ? exp2(s) : 0
#pragma unroll
        for (int nc = 0; nc < 4; ++nc) {
            unsigned w = (nc < 2) ? w0 : w1;
            int bbase = (nc & 1) * 16 + quad * 4;
            bf16x4 pv;
#pragma unroll
            for (int r = 0; r < 4; ++r) {
                float e = __builtin_amdgcn_exp2f(s[nc][r]);
                pv[r] = (bf16)(((w >> (bbase + r)) & 1u) ? e : 0.f);
            }
            *(bf16x4*)&Pw[nc * 16 + quad * 4] = pv;
        }

        bf16x8 pa0 = *(const bf16x8*)&Pr[l * 72 + quad * 8];
        bf16x8 pa1 = *(const bf16x8*)&Pr[l * 72 + 32 + quad * 8];
        l_acc = MFMA(pa0, ones, l_acc);
        l_acc = MFMA(pa1, ones, l_acc);
#pragma unroll
        for (int dc = 0; dc < 4; ++dc) {
            bf16x8 vb0 = frag(VT, dc * 16 + l, quad);
            bf16x8 vb1 = frag(VT, dc * 16 + l, 4 + quad);
            o_acc[dc] = MFMA(pa0, vb0, o_acc[dc]);
            o_acc[dc] = MFMA(pa1, vb1, o_acc[dc]);
        }
    }

    size_t pb = ((size_t)((bh * 32 + it) * 4 + jc)) * 4096;
#pragma unroll
    for (int dc = 0; dc < 4; ++dc)
#pragma unroll
        for (int r = 0; r < 4; ++r)
            Opart[pb + (size_t)(rg * 16 + quad * 4 + r) * 64 + dc * 16 + l] = o_acc[dc][r];
    if (l == 0) {
#pragma unroll
        for (int r = 0; r < 4; ++r)
            Lpart[((bh * 32 + it) * 4 + jc) * 64 + rg * 16 + quad * 4 + r] = l_acc[r];
    }
}

// ---------------- combine partials -> normalized split-bf16 O (R6) ----------------
__global__ __launch_bounds__(256) void attn_combine(
    const float* __restrict__ Opart, const float* __restrict__ Lpart,
    bf16* __restrict__ Oh, bf16* __restrict__ Ol)
{
    int blk = blockIdx.x;
    int bh = blk >> 5, it = blk & 31;
    int t = threadIdx.x;
    int row = t >> 2, dseg = (t & 3) << 4;

    float acc[16] = {};
    float lsum = 0.f;
#pragma unroll
    for (int jc = 0; jc < 4; ++jc) {
        const float* Op = Opart + ((size_t)(blk * 4 + jc)) * 4096 + (size_t)row * 64 + dseg;
#pragma unroll
        for (int u = 0; u < 4; ++u) {
            float4 v = *(const float4*)&Op[u * 4];
            acc[u * 4 + 0] += v.x; acc[u * 4 + 1] += v.y;
            acc[u * 4 + 2] += v.z; acc[u * 4 + 3] += v.w;
        }
        lsum += Lpart[(blk * 4 + jc) * 64 + row];
    }
    float inv = 1.0f / lsum;
    int b = bh >> 3, h = bh & 7, tok = it * 64 + row;
    size_t base = ((size_t)b * 2048 + tok) * 512 + h * 64 + dseg;
    bf16x8 oh0, oh1, ol0, ol1;
#pragma unroll
    for (int u = 0; u < 8; ++u) {
        float v0 = acc[u] * inv, v1 = acc[8 + u] * inv;
        bf16 h0 = (bf16)v0, h1 = (bf16)v1;
        oh0[u] = h0; ol0[u] = (bf16)(v0 - (float)h0);
        oh1[u] = h1; ol1[u] = (bf16)(v1 - (float)h1);
    }
    *(bf16x8*)&Oh[base] = oh0;
    *(bf16x8*)&Oh[base + 8] = oh1;
    *(bf16x8*)&Ol[base] = ol0;
    *(bf16x8*)&Ol[base + 8] = ol1;
}

// ---------------- output projection, LDS-staged split-bf16 (R6) ----------------
__global__ __launch_bounds__(256) void gemm_out(
    const bf16* __restrict__ Ah, const bf16* __restrict__ Al,
    const bf16* __restrict__ Wh, const bf16* __restrict__ Wl,
    float* __restrict__ C)
{
    __shared__ bf16 AhT[4096], AlT[4096], WhT[4096], WlT[4096];
    int bid = blockIdx.x;
    int m0b = bid & 63, n0 = bid >> 6;
    int t = threadIdx.x, wave = t >> 6, lane = t & 63, l = lane & 15, quad = lane >> 4;
    int m0 = m0b * 64 + wave * 16;
    int nb = n0 * 64;
    f32x4 acc[4] = {};
    for (int k0 = 0; k0 < 512; k0 += 64) {
        __syncthreads();
        stage_tile256(AhT, Ah + (size_t)m0b * 64 * 512 + k0, 512, t);
        stage_tile256(AlT, Al + (size_t)m0b * 64 * 512 + k0, 512, t);
        stage_tile256(WhT, Wh + (size_t)nb * 512 + k0, 512, t);
        stage_tile256(WlT, Wl + (size_t)nb * 512 + k0, 512, t);
        __syncthreads();
        bf16x8 ah0 = frag(AhT, wave * 16 + l, quad);
        bf16x8 ah1 = frag(AhT, wave * 16 + l, 4 + quad);
        bf16x8 al0 = frag(AlT, wave * 16 + l, quad);
        bf16x8 al1 = frag(AlT, wave * 16 + l, 4 + quad);
#pragma unroll
        for (int nc = 0; nc < 4; ++nc) {
            bf16x8 bh0 = frag(WhT, nc * 16 + l, quad);
            bf16x8 bh1 = frag(WhT, nc * 16 + l, 4 + quad);
            bf16x8 bl0 = frag(WlT, nc * 16 + l, quad);
            bf16x8 bl1 = frag(WlT, nc * 16 + l, 4 + quad);
            acc[nc] = MFMA(ah0, bh0, acc[nc]);
            acc[nc] = MFMA(ah1, bh1, acc[nc]);
            acc[nc] = MFMA(ah0, bl0, acc[nc]);
            acc[nc] = MFMA(ah1, bl1, acc[nc]);
            acc[nc] = MFMA(al0, bh0, acc[nc]);
            acc[nc] = MFMA(al1, bh1, acc[nc]);
        }
    }
#pragma unroll
    for (int nc = 0; nc < 4; ++nc)
#pragma unroll
        for (int r = 0; r < 4; ++r)
            C[(size_t)(m0 + quad * 4 + r) * 512 + nb + nc * 16 + l] = acc[nc][r];
}

extern "C" void kernel_launch(void* const* d_in, const int* in_sizes, int n_in,
                              void* d_out, int out_size, void* d_ws, size_t ws_size,
                              hipStream_t stream) {
    const float* x = (const float*)d_in[0];
    const float* Wq = (const float*)d_in[1];
    const float* Wk = (const float*)d_in[2];
    const float* Wv = (const float*)d_in[3];
    const float* Wo = (const float*)d_in[4];
    const int* seqm = (const int*)d_in[5];
    const int* spm = (const int*)d_in[6];
    float* out = (float*)d_out;

    const size_t E = 2097152;            // 2*2048*512
    bf16* xb = (bf16*)d_ws;
    bf16* Wb = xb + E;
    bf16* Woh = Wb + 786432;
    bf16* Wol = Woh + 262144;
    bf16* Qg = Wol + 262144;
    bf16* Kg = Qg + E;
    bf16* Vtg = Kg + E;                  // [bh][64][2048]
    bf16* Ohb = Vtg + E;
    bf16* Olb = Ohb + E;
    unsigned* pseq = (unsigned*)(Olb + E);
    unsigned* psp = pseq + 262144;
    float* Opart = (float*)(psp + 262144);       // 2048 x 4096 fp32 = 32 MB
    float* Lpart = Opart + (size_t)2048 * 4096;  // 0.5 MB

    hipLaunchKernelGGL(prep, dim3(3584), dim3(256), 0, stream,
                       seqm, spm, x, Wq, Wk, Wv, Wo, pseq, psp, xb, Wb, Woh, Wol);
    hipLaunchKernelGGL(gemm_qkv, dim3(768), dim3(256), 0, stream, xb, Wb, Qg, Kg, Vtg);
    hipLaunchKernelGGL(attn_kernel, dim3(2048), dim3(256), 0, stream,
                       Qg, Kg, Vtg, pseq, psp, Opart, Lpart);
    hipLaunchKernelGGL(attn_combine, dim3(512), dim3(256), 0, stream, Opart, Lpart, Ohb, Olb);
    hipLaunchKernelGGL(gemm_out, dim3(512), dim3(256), 0, stream, Ohb, Olb, Woh, Wol, out);
}